// Round 12
// baseline (305.476 us; speedup 1.0000x reference)
//
#include <hip/hip_runtime.h>
#include <hip/hip_bf16.h>

#define NSEG 50000

typedef __attribute__((ext_vector_type(4))) float f32x4;
typedef __attribute__((ext_vector_type(8))) short s16x8;

static __device__ __forceinline__ unsigned short f2bf(float f) {
  unsigned int u = __float_as_uint(f);
  u += 0x7fffu + ((u >> 16) & 1u);   // round-to-nearest-even
  return (unsigned short)(u >> 16);
}

static __device__ __forceinline__ s16x8 pack_bf16x8(const float* p) {
  float4 p0 = *(const float4*)(p);
  float4 p1 = *(const float4*)(p + 4);
  s16x8 v;
  v[0] = (short)f2bf(p0.x); v[1] = (short)f2bf(p0.y);
  v[2] = (short)f2bf(p0.z); v[3] = (short)f2bf(p0.w);
  v[4] = (short)f2bf(p1.x); v[5] = (short)f2bf(p1.y);
  v[6] = (short)f2bf(p1.z); v[7] = (short)f2bf(p1.w);
  return v;
}

// ---------------------------------------------------------------------------
// prep: Wb = bf16(W) [256x128];  wb_cat[16][128] bf16 (rows 0-7: a_src-folded
// heads, rows 8-15: a_tgt-folded);  denom = 0.
// ---------------------------------------------------------------------------
__global__ __launch_bounds__(256) void prep_kernel(
    const float* __restrict__ W, const float* __restrict__ a_src,
    const float* __restrict__ a_tgt, unsigned short* __restrict__ Wb,
    unsigned short* __restrict__ wb_cat, float* __restrict__ denom) {
  int t = blockIdx.x * 256 + threadIdx.x;
  if (t < 32768) Wb[t] = f2bf(W[t]);
  if (t < 2048) {
    int row = t >> 7, k = t & 127;
    int h = row & 7;
    const float* a = (row < 8) ? a_src : a_tgt;
    float acc = 0.f;
    for (int f = 0; f < 32; ++f) acc += W[(h * 32 + f) * 128 + k] * a[h * 32 + f];
    wb_cat[t] = f2bf(acc);
  }
  if (t < NSEG * 8) denom[t] = 0.f;
}

// ---------------------------------------------------------------------------
// score: MFMA, A = wb_cat (16 rows x 128 K), B = msg rows (K x 16 edges).
// C layout: row = kgrp*4+r (head), col = lane&15 (edge).
// ---------------------------------------------------------------------------
__global__ __launch_bounds__(256) void score_kernel(
    const float* __restrict__ msg, const int* __restrict__ index,
    const unsigned short* __restrict__ wb_cat, float* __restrict__ ex,
    float* __restrict__ denom, int n) {
  int tid = threadIdx.x;
  int w = tid >> 6, l = tid & 63;
  int lcol = l & 15;   // A row / B col (edge) within tile
  int kgrp = l >> 4;   // k-chunk of 8
  int ge = blockIdx.x * 64 + w * 16 + lcol;
  int ga = ge < n ? ge : n - 1;
  const float* rs = msg + (size_t)ga * 128;                // msg_src row
  const float* rt = msg + ((size_t)ga + (size_t)n) * 128;  // msg_tgt row

  s16x8 afrag[4];
#pragma unroll
  for (int kk = 0; kk < 4; ++kk)
    afrag[kk] = *(const s16x8*)(wb_cat + lcol * 128 + kk * 32 + kgrp * 8);

  f32x4 ds = {0.f, 0.f, 0.f, 0.f};
  f32x4 dt = {0.f, 0.f, 0.f, 0.f};
#pragma unroll
  for (int kk = 0; kk < 4; ++kk) {
    int k0 = kk * 32 + kgrp * 8;
    s16x8 bs = pack_bf16x8(rs + k0);
    ds = __builtin_amdgcn_mfma_f32_16x16x32_bf16(afrag[kk], bs, ds, 0, 0, 0);
    s16x8 bt = pack_bf16x8(rt + k0);
    dt = __builtin_amdgcn_mfma_f32_16x16x32_bf16(afrag[kk], bt, dt, 0, 0, 0);
  }

  f32x4 evv;
#pragma unroll
  for (int r = 0; r < 4; ++r) {
    float tv = __shfl_xor(dt[r], 32);   // lane kgrp -> kgrp+2: dt row h+8
    float s = ds[r] + tv;
    s = s > 0.f ? s : 0.2f * s;         // leaky_relu, NEG_SLOPE=0.2
    evv[r] = __expf(s);
  }
  if (kgrp < 2 && ge < n) {
    int seg = index[ge];
#pragma unroll
    for (int r = 0; r < 4; ++r) atomicAdd(&denom[seg * 8 + kgrp * 4 + r], evv[r]);
    *(f32x4*)(ex + (size_t)ge * 8 + kgrp * 4) = evv;
  }
}

// ---------------------------------------------------------------------------
// gemm v2: 512 threads = 8 waves; wave w owns features [w*32, w*32+32).
// ALL global loads (afrag, bfrag for all 4 edge-tiles, att/ex/denom/index)
// issue BEFORE any store -> per-wave vmcnt FIFO never forces a store drain
// (vmcnt retires in issue order; any load-wait after a store would drain it).
// Then a load-free loop: MFMA -> LDS stage -> 1 KB NT stores, raw barriers.
// ---------------------------------------------------------------------------
__global__ __launch_bounds__(512, 4) void gemm_kernel(
    const float* __restrict__ msg, const int* __restrict__ index,
    const unsigned short* __restrict__ Wb, const float* __restrict__ ex,
    const float* __restrict__ denom, float* __restrict__ out, int n) {
  __shared__ float att_lds[64][9];
  __shared__ float stg[2][16][260];   // [half][edge][feat], stride 260
  int tid = threadIdx.x;
  int w = tid >> 6, l = tid & 63;     // 8 waves
  int lcol = l & 15, kgrp = l >> 4;
  int mbase = blockIdx.x * 64;

  // att for the block's 64 edges x 8 heads (one entry per thread)
  {
    int r = tid >> 3, h = tid & 7;
    int ge = mbase + r;
    float a = 0.f;
    if (ge < n) {
      int seg = index[ge];
      a = ex[(size_t)ge * 8 + h] / (denom[seg * 8 + h] + 1e-16f);
    }
    att_lds[r][h] = a;
  }

  // A-frags: wave w's 2 feature-tiles (Wb is L2-resident)
  s16x8 afrag[2][4];
#pragma unroll
  for (int ct = 0; ct < 2; ++ct) {
    int feat = w * 32 + ct * 16 + lcol;
#pragma unroll
    for (int kk = 0; kk < 4; ++kk)
      afrag[ct][kk] = *(const s16x8*)(Wb + (size_t)feat * 128 + kk * 32 + kgrp * 8);
  }

  // B-frags: ALL 4 edge-tiles packed upfront (64 VGPR) — no loads after this
  s16x8 bfrag[4][4];
#pragma unroll
  for (int t = 0; t < 4; ++t) {
    int grow = mbase + t * 16 + lcol;
    int ga = grow < n ? grow : n - 1;
    const float* brow = msg + ((size_t)ga + (size_t)n) * 128;  // msg_tgt row
#pragma unroll
    for (int kk = 0; kk < 4; ++kk)
      bfrag[t][kk] = pack_bf16x8(brow + kk * 32 + kgrp * 8);
  }

  __syncthreads();  // att_lds ready (no stores outstanding yet)

#pragma unroll
  for (int t = 0; t < 4; ++t) {
    // compute + stage into LDS
#pragma unroll
    for (int ct = 0; ct < 2; ++ct) {
      f32x4 acc = {0.f, 0.f, 0.f, 0.f};
#pragma unroll
      for (int kk = 0; kk < 4; ++kk)
        acc = __builtin_amdgcn_mfma_f32_16x16x32_bf16(afrag[ct][kk], bfrag[t][kk], acc, 0, 0, 0);
      int f0 = w * 32 + ct * 16 + kgrp * 4;
      float a = att_lds[t * 16 + lcol][f0 >> 5];
      *(f32x4*)&stg[0][lcol][f0] = acc * a;
      *(f32x4*)&stg[1][lcol][f0] = acc;
    }
    asm volatile("s_waitcnt lgkmcnt(0)" ::: "memory");  // LDS writes visible
    __builtin_amdgcn_s_barrier();                       // no vmcnt drain

    // 32 rows of 1 KB (16 edges x 2 halves); wave w stores rows rnd*8+w
#pragma unroll
    for (int rnd = 0; rnd < 4; ++rnd) {
      int row = rnd * 8 + w;
      int half = row >> 4, er = row & 15;
      int ge = mbase + t * 16 + er;
      if (ge < n) {
        f32x4 v = *(const f32x4*)(&stg[half][er][0] + l * 4);
        size_t base = half ? ((size_t)ge + (size_t)n) * 256 : (size_t)ge * 256;
        __builtin_nontemporal_store(v, (f32x4*)(out + base + l * 4));
      }
    }
    asm volatile("s_waitcnt lgkmcnt(0)" ::: "memory");  // LDS reads done
    __builtin_amdgcn_s_barrier();                       // stores stay in flight
  }
}

// ---------------------------------------------------------------------------
extern "C" void kernel_launch(void* const* d_in, const int* in_sizes, int n_in,
                              void* d_out, int out_size, void* d_ws, size_t ws_size,
                              hipStream_t stream) {
  const float* messages = (const float*)d_in[0];
  const float* W        = (const float*)d_in[1];
  const float* a_src    = (const float*)d_in[2];
  const float* a_tgt    = (const float*)d_in[3];
  const int*   index    = (const int*)d_in[4];
  int n = in_sizes[4];  // n_edges = 250000

  char* ws = (char*)d_ws;
  unsigned short* Wb     = (unsigned short*)(ws);             // 64 KB
  unsigned short* wb_cat = (unsigned short*)(ws + 65536);     // 4 KB
  float* denom           = (float*)(ws + 69632);              // 1.6 MB
  float* ex              = (float*)(ws + 69632 + 1600000);    // 8 MB
  float* out = (float*)d_out;

  int nblk = (n + 63) / 64;
  prep_kernel<<<(NSEG * 8 + 255) / 256, 256, 0, stream>>>(W, a_src, a_tgt, Wb,
                                                          wb_cat, denom);
  score_kernel<<<nblk, 256, 0, stream>>>(messages, index, wb_cat, ex, denom, n);
  gemm_kernel<<<nblk, 512, 0, stream>>>(messages, index, Wb, ex, denom, out, n);
}

// Round 13
// 187.724 us; speedup vs baseline: 1.6273x; 1.6273x over previous
//
#include <hip/hip_runtime.h>
#include <hip/hip_bf16.h>

#define NSEG 50000

typedef __attribute__((ext_vector_type(4))) float f32x4;
typedef __attribute__((ext_vector_type(8))) short s16x8;

static __device__ __forceinline__ unsigned short f2bf(float f) {
  unsigned int u = __float_as_uint(f);
  u += 0x7fffu + ((u >> 16) & 1u);   // round-to-nearest-even
  return (unsigned short)(u >> 16);
}

static __device__ __forceinline__ s16x8 pack_bf16x8(const float* p) {
  float4 p0 = *(const float4*)(p);
  float4 p1 = *(const float4*)(p + 4);
  s16x8 v;
  v[0] = (short)f2bf(p0.x); v[1] = (short)f2bf(p0.y);
  v[2] = (short)f2bf(p0.z); v[3] = (short)f2bf(p0.w);
  v[4] = (short)f2bf(p1.x); v[5] = (short)f2bf(p1.y);
  v[6] = (short)f2bf(p1.z); v[7] = (short)f2bf(p1.w);
  return v;
}

static __device__ __forceinline__ s16x8 pack_raw(const float4& a, const float4& b) {
  s16x8 v;
  v[0] = (short)f2bf(a.x); v[1] = (short)f2bf(a.y);
  v[2] = (short)f2bf(a.z); v[3] = (short)f2bf(a.w);
  v[4] = (short)f2bf(b.x); v[5] = (short)f2bf(b.y);
  v[6] = (short)f2bf(b.z); v[7] = (short)f2bf(b.w);
  return v;
}

// ---------------------------------------------------------------------------
// prep: Wb = bf16(W) [256x128];  wb_cat[16][128] bf16 (rows 0-7: a_src-folded
// heads, rows 8-15: a_tgt-folded);  denom = 0.
// ---------------------------------------------------------------------------
__global__ __launch_bounds__(256) void prep_kernel(
    const float* __restrict__ W, const float* __restrict__ a_src,
    const float* __restrict__ a_tgt, unsigned short* __restrict__ Wb,
    unsigned short* __restrict__ wb_cat, float* __restrict__ denom) {
  int t = blockIdx.x * 256 + threadIdx.x;
  if (t < 32768) Wb[t] = f2bf(W[t]);
  if (t < 2048) {
    int row = t >> 7, k = t & 127;
    int h = row & 7;
    const float* a = (row < 8) ? a_src : a_tgt;
    float acc = 0.f;
    for (int f = 0; f < 32; ++f) acc += W[(h * 32 + f) * 128 + k] * a[h * 32 + f];
    wb_cat[t] = f2bf(acc);
  }
  if (t < NSEG * 8) denom[t] = 0.f;
}

// ---------------------------------------------------------------------------
// score: MFMA, A = wb_cat (16 rows x 128 K), B = msg rows (K x 16 edges).
// (unchanged from R8)
// ---------------------------------------------------------------------------
__global__ __launch_bounds__(256) void score_kernel(
    const float* __restrict__ msg, const int* __restrict__ index,
    const unsigned short* __restrict__ wb_cat, float* __restrict__ ex,
    float* __restrict__ denom, int n) {
  int tid = threadIdx.x;
  int w = tid >> 6, l = tid & 63;
  int lcol = l & 15;
  int kgrp = l >> 4;
  int ge = blockIdx.x * 64 + w * 16 + lcol;
  int ga = ge < n ? ge : n - 1;
  const float* rs = msg + (size_t)ga * 128;
  const float* rt = msg + ((size_t)ga + (size_t)n) * 128;

  s16x8 afrag[4];
#pragma unroll
  for (int kk = 0; kk < 4; ++kk)
    afrag[kk] = *(const s16x8*)(wb_cat + lcol * 128 + kk * 32 + kgrp * 8);

  f32x4 ds = {0.f, 0.f, 0.f, 0.f};
  f32x4 dt = {0.f, 0.f, 0.f, 0.f};
#pragma unroll
  for (int kk = 0; kk < 4; ++kk) {
    int k0 = kk * 32 + kgrp * 8;
    s16x8 bs = pack_bf16x8(rs + k0);
    ds = __builtin_amdgcn_mfma_f32_16x16x32_bf16(afrag[kk], bs, ds, 0, 0, 0);
    s16x8 bt = pack_bf16x8(rt + k0);
    dt = __builtin_amdgcn_mfma_f32_16x16x32_bf16(afrag[kk], bt, dt, 0, 0, 0);
  }

  f32x4 evv;
#pragma unroll
  for (int r = 0; r < 4; ++r) {
    float tv = __shfl_xor(dt[r], 32);
    float s = ds[r] + tv;
    s = s > 0.f ? s : 0.2f * s;         // leaky_relu, NEG_SLOPE=0.2
    evv[r] = __expf(s);
  }
  if (kgrp < 2 && ge < n) {
    int seg = index[ge];
#pragma unroll
    for (int r = 0; r < 4; ++r) atomicAdd(&denom[seg * 8 + kgrp * 4 + r], evv[r]);
    *(f32x4*)(ex + (size_t)ge * 8 + kgrp * 4) = evv;
  }
}

// ---------------------------------------------------------------------------
// gemm v3 = R8 + depth-1 software pipeline ordered for the vmcnt FIFO:
// raw loads for tile t+1 are issued BEFORE tile t's NT stores, so every
// outstanding store is always the NEWEST vmem op; waiting for loads (pack)
// needs only vmcnt(8) and never drains the store stream.
// ---------------------------------------------------------------------------
__global__ __launch_bounds__(256) void gemm_kernel(
    const float* __restrict__ msg, const int* __restrict__ index,
    const unsigned short* __restrict__ Wb, const float* __restrict__ ex,
    const float* __restrict__ denom, float* __restrict__ out, int n) {
  __shared__ float att_lds[64][9];
  __shared__ float stg[2][16][260];
  int tid = threadIdx.x;
  int w = tid >> 6, l = tid & 63;
  int lcol = l & 15, kgrp = l >> 4;
  int mbase = blockIdx.x * 64;

  // prologue raw loads for tile 0 (issued first, overlap att phase)
  float4 raw[8];
  {
    int grow = mbase + lcol;
    int ga = grow < n ? grow : n - 1;
    const float* p = msg + ((size_t)ga + (size_t)n) * 128 + kgrp * 8;
#pragma unroll
    for (int kk = 0; kk < 4; ++kk) {
      raw[kk * 2]     = *(const float4*)(p + kk * 32);
      raw[kk * 2 + 1] = *(const float4*)(p + kk * 32 + 4);
    }
  }

  for (int i = tid; i < 512; i += 256) {
    int r = i >> 3, h = i & 7;
    int ge = mbase + r;
    float a = 0.f;
    if (ge < n) {
      int seg = index[ge];
      a = ex[(size_t)ge * 8 + h] / (denom[seg * 8 + h] + 1e-16f);
    }
    att_lds[r][h] = a;
  }

  s16x8 afrag[4][4];
#pragma unroll
  for (int ct = 0; ct < 4; ++ct) {
    int feat = w * 64 + ct * 16 + lcol;
#pragma unroll
    for (int kk = 0; kk < 4; ++kk)
      afrag[ct][kk] = *(const s16x8*)(Wb + (size_t)feat * 128 + kk * 32 + kgrp * 8);
  }

  __syncthreads();  // att_lds ready; no stores outstanding yet

#pragma unroll
  for (int t = 0; t < 4; ++t) {
    // pack current tile (compiler waits for raw loads; any outstanding
    // NT stores are newer in the FIFO -> not drained)
    s16x8 bfrag[4];
#pragma unroll
    for (int kk = 0; kk < 4; ++kk)
      bfrag[kk] = pack_raw(raw[kk * 2], raw[kk * 2 + 1]);

    // issue raw loads for tile t+1 (before any store of tile t)
    if (t < 3) {
      int grow = mbase + (t + 1) * 16 + lcol;
      int ga = grow < n ? grow : n - 1;
      const float* p = msg + ((size_t)ga + (size_t)n) * 128 + kgrp * 8;
#pragma unroll
      for (int kk = 0; kk < 4; ++kk) {
        raw[kk * 2]     = *(const float4*)(p + kk * 32);
        raw[kk * 2 + 1] = *(const float4*)(p + kk * 32 + 4);
      }
    }

    // compute + stage into LDS
#pragma unroll
    for (int ct = 0; ct < 4; ++ct) {
      f32x4 acc = {0.f, 0.f, 0.f, 0.f};
#pragma unroll
      for (int kk = 0; kk < 4; ++kk)
        acc = __builtin_amdgcn_mfma_f32_16x16x32_bf16(afrag[ct][kk], bfrag[kk], acc, 0, 0, 0);
      int f0 = w * 64 + ct * 16 + kgrp * 4;
      float a = att_lds[t * 16 + lcol][f0 >> 5];
      *(f32x4*)&stg[0][lcol][f0] = acc * a;
      *(f32x4*)&stg[1][lcol][f0] = acc;
    }
    asm volatile("s_waitcnt lgkmcnt(0)" ::: "memory");  // LDS writes visible
    __builtin_amdgcn_s_barrier();                       // no vmcnt drain

    // wave w writes edges er = rnd*4 + w; 1 KB contiguous NT per store
#pragma unroll
    for (int rnd = 0; rnd < 4; ++rnd) {
      int er = rnd * 4 + w;
      int ge = mbase + t * 16 + er;
      if (ge < n) {
        f32x4 v0 = *(const f32x4*)(&stg[0][er][0] + l * 4);
        __builtin_nontemporal_store(v0, (f32x4*)(out + (size_t)ge * 256 + l * 4));
        f32x4 v1 = *(const f32x4*)(&stg[1][er][0] + l * 4);
        __builtin_nontemporal_store(v1, (f32x4*)(out + ((size_t)ge + (size_t)n) * 256 + l * 4));
      }
    }
    asm volatile("s_waitcnt lgkmcnt(0)" ::: "memory");  // LDS reads done
    __builtin_amdgcn_s_barrier();                       // stores stay in flight
  }
}

// ---------------------------------------------------------------------------
extern "C" void kernel_launch(void* const* d_in, const int* in_sizes, int n_in,
                              void* d_out, int out_size, void* d_ws, size_t ws_size,
                              hipStream_t stream) {
  const float* messages = (const float*)d_in[0];
  const float* W        = (const float*)d_in[1];
  const float* a_src    = (const float*)d_in[2];
  const float* a_tgt    = (const float*)d_in[3];
  const int*   index    = (const int*)d_in[4];
  int n = in_sizes[4];  // n_edges = 250000

  char* ws = (char*)d_ws;
  unsigned short* Wb     = (unsigned short*)(ws);             // 64 KB
  unsigned short* wb_cat = (unsigned short*)(ws + 65536);     // 4 KB
  float* denom           = (float*)(ws + 69632);              // 1.6 MB
  float* ex              = (float*)(ws + 69632 + 1600000);    // 8 MB
  float* out = (float*)d_out;

  int nblk = (n + 63) / 64;
  prep_kernel<<<(NSEG * 8 + 255) / 256, 256, 0, stream>>>(W, a_src, a_tgt, Wb,
                                                          wb_cat, denom);
  score_kernel<<<nblk, 256, 0, stream>>>(messages, index, wb_cat, ex, denom, n);
  gemm_kernel<<<nblk, 256, 0, stream>>>(messages, index, Wb, ex, denom, out, n);
}

// Round 15
// 180.589 us; speedup vs baseline: 1.6915x; 1.0395x over previous
//
#include <hip/hip_runtime.h>
#include <hip/hip_bf16.h>

#define NSEG 50000

typedef __attribute__((ext_vector_type(4))) float f32x4;
typedef __attribute__((ext_vector_type(8))) short s16x8;

static __device__ __forceinline__ unsigned short f2bf(float f) {
  unsigned int u = __float_as_uint(f);
  u += 0x7fffu + ((u >> 16) & 1u);   // round-to-nearest-even
  return (unsigned short)(u >> 16);
}

static __device__ __forceinline__ s16x8 pack_raw(const f32x4& a, const f32x4& b) {
  s16x8 v;
  v[0] = (short)f2bf(a.x); v[1] = (short)f2bf(a.y);
  v[2] = (short)f2bf(a.z); v[3] = (short)f2bf(a.w);
  v[4] = (short)f2bf(b.x); v[5] = (short)f2bf(b.y);
  v[6] = (short)f2bf(b.z); v[7] = (short)f2bf(b.w);
  return v;
}

static __device__ __forceinline__ s16x8 pack_bf16x8(const float* p) {
  f32x4 p0 = *(const f32x4*)(p);
  f32x4 p1 = *(const f32x4*)(p + 4);
  return pack_raw(p0, p1);
}

// NT load variant: stream without LLC allocation (preserve LLC for msg_tgt)
static __device__ __forceinline__ s16x8 pack_bf16x8_nt(const float* p) {
  f32x4 p0 = __builtin_nontemporal_load((const f32x4*)p);
  f32x4 p1 = __builtin_nontemporal_load((const f32x4*)(p + 4));
  return pack_raw(p0, p1);
}

// ---------------------------------------------------------------------------
// prep: Wb = bf16(W) [256x128];  wb_cat[16][128] bf16 (rows 0-7: a_src-folded
// heads, rows 8-15: a_tgt-folded);  denom = 0.
// ---------------------------------------------------------------------------
__global__ __launch_bounds__(256) void prep_kernel(
    const float* __restrict__ W, const float* __restrict__ a_src,
    const float* __restrict__ a_tgt, unsigned short* __restrict__ Wb,
    unsigned short* __restrict__ wb_cat, float* __restrict__ denom) {
  int t = blockIdx.x * 256 + threadIdx.x;
  if (t < 32768) Wb[t] = f2bf(W[t]);
  if (t < 2048) {
    int row = t >> 7, k = t & 127;
    int h = row & 7;
    const float* a = (row < 8) ? a_src : a_tgt;
    float acc = 0.f;
    for (int f = 0; f < 32; ++f) acc += W[(h * 32 + f) * 128 + k] * a[h * 32 + f];
    wb_cat[t] = f2bf(acc);
  }
  if (t < NSEG * 8) denom[t] = 0.f;
}

// ---------------------------------------------------------------------------
// score: MFMA, A = wb_cat (16 rows x 128 K), B = msg rows (K x 16 edges).
// R15: msg_src read NONTEMPORAL (no LLC alloc -> msg_tgt stays resident for
// the gemm's re-read); msg_tgt read cached.
// ---------------------------------------------------------------------------
__global__ __launch_bounds__(256) void score_kernel(
    const float* __restrict__ msg, const int* __restrict__ index,
    const unsigned short* __restrict__ wb_cat, float* __restrict__ ex,
    float* __restrict__ denom, int n) {
  int tid = threadIdx.x;
  int w = tid >> 6, l = tid & 63;
  int lcol = l & 15;
  int kgrp = l >> 4;
  int ge = blockIdx.x * 64 + w * 16 + lcol;
  int ga = ge < n ? ge : n - 1;
  const float* rs = msg + (size_t)ga * 128;                // msg_src row
  const float* rt = msg + ((size_t)ga + (size_t)n) * 128;  // msg_tgt row

  s16x8 afrag[4];
#pragma unroll
  for (int kk = 0; kk < 4; ++kk)
    afrag[kk] = *(const s16x8*)(wb_cat + lcol * 128 + kk * 32 + kgrp * 8);

  f32x4 ds = {0.f, 0.f, 0.f, 0.f};
  f32x4 dt = {0.f, 0.f, 0.f, 0.f};
#pragma unroll
  for (int kk = 0; kk < 4; ++kk) {
    int k0 = kk * 32 + kgrp * 8;
    s16x8 bs = pack_bf16x8_nt(rs + k0);   // NT: no LLC pollution
    ds = __builtin_amdgcn_mfma_f32_16x16x32_bf16(afrag[kk], bs, ds, 0, 0, 0);
    s16x8 bt = pack_bf16x8(rt + k0);      // cached: wanted in LLC for gemm
    dt = __builtin_amdgcn_mfma_f32_16x16x32_bf16(afrag[kk], bt, dt, 0, 0, 0);
  }

  f32x4 evv;
#pragma unroll
  for (int r = 0; r < 4; ++r) {
    float tv = __shfl_xor(dt[r], 32);
    float s = ds[r] + tv;
    s = s > 0.f ? s : 0.2f * s;         // leaky_relu, NEG_SLOPE=0.2
    evv[r] = __expf(s);
  }
  if (kgrp < 2 && ge < n) {
    int seg = index[ge];
#pragma unroll
    for (int r = 0; r < 4; ++r) atomicAdd(&denom[seg * 8 + kgrp * 4 + r], evv[r]);
    *(f32x4*)(ex + (size_t)ge * 8 + kgrp * 4) = evv;
  }
}

// ---------------------------------------------------------------------------
// gemm: R8 structure, 128-edge blocks (8 t-tiles): Wb/att amortized 2x,
// 128 KB contiguous store region per block half. LDS-bounce + 1 KB NT stores
// + raw barriers (no vmcnt drain).
// ---------------------------------------------------------------------------
__global__ __launch_bounds__(256) void gemm_kernel(
    const float* __restrict__ msg, const int* __restrict__ index,
    const unsigned short* __restrict__ Wb, const float* __restrict__ ex,
    const float* __restrict__ denom, float* __restrict__ out, int n) {
  __shared__ float att_lds[128][9];
  __shared__ float stg[2][16][260];
  int tid = threadIdx.x;
  int w = tid >> 6, l = tid & 63;
  int lcol = l & 15, kgrp = l >> 4;
  int mbase = blockIdx.x * 128;

  for (int i = tid; i < 1024; i += 256) {
    int r = i >> 3, h = i & 7;
    int ge = mbase + r;
    float a = 0.f;
    if (ge < n) {
      int seg = index[ge];
      a = ex[(size_t)ge * 8 + h] / (denom[seg * 8 + h] + 1e-16f);
    }
    att_lds[r][h] = a;
  }

  // A-frags: wave w's 4 feature-tiles, loaded once (Wb is L2-resident)
  s16x8 afrag[4][4];
#pragma unroll
  for (int ct = 0; ct < 4; ++ct) {
    int feat = w * 64 + ct * 16 + lcol;
#pragma unroll
    for (int kk = 0; kk < 4; ++kk)
      afrag[ct][kk] = *(const s16x8*)(Wb + (size_t)feat * 128 + kk * 32 + kgrp * 8);
  }

  __syncthreads();

  for (int t = 0; t < 8; ++t) {
    int grow = mbase + t * 16 + lcol;
    int ga = grow < n ? grow : n - 1;
    const float* brow = msg + ((size_t)ga + (size_t)n) * 128;  // msg_tgt row

    s16x8 bfrag[4];
#pragma unroll
    for (int kk = 0; kk < 4; ++kk)
      bfrag[kk] = pack_bf16x8(brow + kk * 32 + kgrp * 8);

    // compute + stage into LDS
#pragma unroll
    for (int ct = 0; ct < 4; ++ct) {
      f32x4 acc = {0.f, 0.f, 0.f, 0.f};
#pragma unroll
      for (int kk = 0; kk < 4; ++kk)
        acc = __builtin_amdgcn_mfma_f32_16x16x32_bf16(afrag[ct][kk], bfrag[kk], acc, 0, 0, 0);
      int f0 = w * 64 + ct * 16 + kgrp * 4;
      float a = att_lds[t * 16 + lcol][f0 >> 5];
      *(f32x4*)&stg[0][lcol][f0] = acc * a;
      *(f32x4*)&stg[1][lcol][f0] = acc;
    }
    asm volatile("s_waitcnt lgkmcnt(0)" ::: "memory");  // LDS writes visible
    __builtin_amdgcn_s_barrier();                       // no vmcnt drain

    // wave w writes edges er = rnd*4 + w; 1 KB contiguous NT per store
#pragma unroll
    for (int rnd = 0; rnd < 4; ++rnd) {
      int er = rnd * 4 + w;
      int ge = mbase + t * 16 + er;
      if (ge < n) {
        f32x4 v0 = *(const f32x4*)(&stg[0][er][0] + l * 4);
        __builtin_nontemporal_store(v0, (f32x4*)(out + (size_t)ge * 256 + l * 4));
        f32x4 v1 = *(const f32x4*)(&stg[1][er][0] + l * 4);
        __builtin_nontemporal_store(v1, (f32x4*)(out + ((size_t)ge + (size_t)n) * 256 + l * 4));
      }
    }
    asm volatile("s_waitcnt lgkmcnt(0)" ::: "memory");  // LDS reads done
    __builtin_amdgcn_s_barrier();                       // stores stay in flight
  }
}

// ---------------------------------------------------------------------------
extern "C" void kernel_launch(void* const* d_in, const int* in_sizes, int n_in,
                              void* d_out, int out_size, void* d_ws, size_t ws_size,
                              hipStream_t stream) {
  const float* messages = (const float*)d_in[0];
  const float* W        = (const float*)d_in[1];
  const float* a_src    = (const float*)d_in[2];
  const float* a_tgt    = (const float*)d_in[3];
  const int*   index    = (const int*)d_in[4];
  int n = in_sizes[4];  // n_edges = 250000

  char* ws = (char*)d_ws;
  unsigned short* Wb     = (unsigned short*)(ws);             // 64 KB
  unsigned short* wb_cat = (unsigned short*)(ws + 65536);     // 4 KB
  float* denom           = (float*)(ws + 69632);              // 1.6 MB
  float* ex              = (float*)(ws + 69632 + 1600000);    // 8 MB
  float* out = (float*)d_out;

  prep_kernel<<<(NSEG * 8 + 255) / 256, 256, 0, stream>>>(W, a_src, a_tgt, Wb,
                                                          wb_cat, denom);
  score_kernel<<<(n + 63) / 64, 256, 0, stream>>>(messages, index, wb_cat, ex,
                                                  denom, n);
  gemm_kernel<<<(n + 127) / 128, 256, 0, stream>>>(messages, index, Wb, ex,
                                                   denom, out, n);
}

// Round 16
// 169.329 us; speedup vs baseline: 1.8040x; 1.0665x over previous
//
#include <hip/hip_runtime.h>
#include <hip/hip_bf16.h>

#define NSEG 50000

typedef __attribute__((ext_vector_type(4))) float f32x4;
typedef __attribute__((ext_vector_type(8))) short s16x8;

static __device__ __forceinline__ unsigned short f2bf(float f) {
  unsigned int u = __float_as_uint(f);
  u += 0x7fffu + ((u >> 16) & 1u);   // round-to-nearest-even
  return (unsigned short)(u >> 16);
}

static __device__ __forceinline__ s16x8 pack_raw(const f32x4& a, const f32x4& b) {
  s16x8 v;
  v[0] = (short)f2bf(a.x); v[1] = (short)f2bf(a.y);
  v[2] = (short)f2bf(a.z); v[3] = (short)f2bf(a.w);
  v[4] = (short)f2bf(b.x); v[5] = (short)f2bf(b.y);
  v[6] = (short)f2bf(b.z); v[7] = (short)f2bf(b.w);
  return v;
}

static __device__ __forceinline__ s16x8 pack_bf16x8(const float* p) {
  f32x4 p0 = *(const f32x4*)(p);
  f32x4 p1 = *(const f32x4*)(p + 4);
  return pack_raw(p0, p1);
}

// NT load variant: stream without LLC allocation (preserve LLC for msg_tgt)
static __device__ __forceinline__ s16x8 pack_bf16x8_nt(const float* p) {
  f32x4 p0 = __builtin_nontemporal_load((const f32x4*)p);
  f32x4 p1 = __builtin_nontemporal_load((const f32x4*)(p + 4));
  return pack_raw(p0, p1);
}

// packed bf16 atomic add: one 4 B atomic covers 2 heads (halves atomic ops)
static __device__ __forceinline__ void atomic_pk_add_bf16(unsigned short* addr,
                                                          unsigned int packed2) {
  asm volatile("global_atomic_pk_add_bf16 %0, %1, off"
               :: "v"(addr), "v"(packed2) : "memory");
}

// ---------------------------------------------------------------------------
// prep: Wb = bf16(W) [256x128];  wb_cat[16][128] bf16 (rows 0-7: a_src-folded
// heads, rows 8-15: a_tgt-folded);  denom (bf16) = 0.
// ---------------------------------------------------------------------------
__global__ __launch_bounds__(256) void prep_kernel(
    const float* __restrict__ W, const float* __restrict__ a_src,
    const float* __restrict__ a_tgt, unsigned short* __restrict__ Wb,
    unsigned short* __restrict__ wb_cat, unsigned short* __restrict__ denom) {
  int t = blockIdx.x * 256 + threadIdx.x;
  if (t < 32768) Wb[t] = f2bf(W[t]);
  if (t < 2048) {
    int row = t >> 7, k = t & 127;
    int h = row & 7;
    const float* a = (row < 8) ? a_src : a_tgt;
    float acc = 0.f;
    for (int f = 0; f < 32; ++f) acc += W[(h * 32 + f) * 128 + k] * a[h * 32 + f];
    wb_cat[t] = f2bf(acc);
  }
  if (t < NSEG * 8) denom[t] = 0;
}

// ---------------------------------------------------------------------------
// score: MFMA, A = wb_cat (16 rows x 128 K), B = msg rows (K x 16 edges).
// msg_src NT-read; msg_tgt cached. Denominator via packed-bf16 atomics:
// 2 ops/lane (4/edge) instead of 4 f32 ops/lane (8/edge).
// ---------------------------------------------------------------------------
__global__ __launch_bounds__(256) void score_kernel(
    const float* __restrict__ msg, const int* __restrict__ index,
    const unsigned short* __restrict__ wb_cat, float* __restrict__ ex,
    unsigned short* __restrict__ denom, int n) {
  int tid = threadIdx.x;
  int w = tid >> 6, l = tid & 63;
  int lcol = l & 15;
  int kgrp = l >> 4;
  int ge = blockIdx.x * 64 + w * 16 + lcol;
  int ga = ge < n ? ge : n - 1;
  const float* rs = msg + (size_t)ga * 128;                // msg_src row
  const float* rt = msg + ((size_t)ga + (size_t)n) * 128;  // msg_tgt row

  s16x8 afrag[4];
#pragma unroll
  for (int kk = 0; kk < 4; ++kk)
    afrag[kk] = *(const s16x8*)(wb_cat + lcol * 128 + kk * 32 + kgrp * 8);

  f32x4 ds = {0.f, 0.f, 0.f, 0.f};
  f32x4 dt = {0.f, 0.f, 0.f, 0.f};
#pragma unroll
  for (int kk = 0; kk < 4; ++kk) {
    int k0 = kk * 32 + kgrp * 8;
    s16x8 bs = pack_bf16x8_nt(rs + k0);   // NT: no LLC pollution
    ds = __builtin_amdgcn_mfma_f32_16x16x32_bf16(afrag[kk], bs, ds, 0, 0, 0);
    s16x8 bt = pack_bf16x8(rt + k0);      // cached: wanted in LLC for gemm
    dt = __builtin_amdgcn_mfma_f32_16x16x32_bf16(afrag[kk], bt, dt, 0, 0, 0);
  }

  f32x4 evv;
#pragma unroll
  for (int r = 0; r < 4; ++r) {
    float tv = __shfl_xor(dt[r], 32);
    float s = ds[r] + tv;
    s = s > 0.f ? s : 0.2f * s;         // leaky_relu, NEG_SLOPE=0.2
    evv[r] = __expf(s);
  }
  if (kgrp < 2 && ge < n) {
    int seg = index[ge];
    unsigned int p0 = (unsigned int)f2bf(evv[0]) | ((unsigned int)f2bf(evv[1]) << 16);
    unsigned int p1 = (unsigned int)f2bf(evv[2]) | ((unsigned int)f2bf(evv[3]) << 16);
    atomic_pk_add_bf16(&denom[seg * 8 + kgrp * 4], p0);
    atomic_pk_add_bf16(&denom[seg * 8 + kgrp * 4 + 2], p1);
    *(f32x4*)(ex + (size_t)ge * 8 + kgrp * 4) = evv;
  }
}

// ---------------------------------------------------------------------------
// gemm: 128-edge blocks (8 t-tiles), LDS-bounce + 1 KB NT stores + raw
// barriers. denom read as bf16.
// ---------------------------------------------------------------------------
__global__ __launch_bounds__(256) void gemm_kernel(
    const float* __restrict__ msg, const int* __restrict__ index,
    const unsigned short* __restrict__ Wb, const float* __restrict__ ex,
    const unsigned short* __restrict__ denom, float* __restrict__ out, int n) {
  __shared__ float att_lds[128][9];
  __shared__ float stg[2][16][260];
  int tid = threadIdx.x;
  int w = tid >> 6, l = tid & 63;
  int lcol = l & 15, kgrp = l >> 4;
  int mbase = blockIdx.x * 128;

  for (int i = tid; i < 1024; i += 256) {
    int r = i >> 3, h = i & 7;
    int ge = mbase + r;
    float a = 0.f;
    if (ge < n) {
      int seg = index[ge];
      float dv = __uint_as_float(((unsigned int)denom[seg * 8 + h]) << 16);
      a = ex[(size_t)ge * 8 + h] / (dv + 1e-16f);
    }
    att_lds[r][h] = a;
  }

  // A-frags: wave w's 4 feature-tiles, loaded once (Wb is L2-resident)
  s16x8 afrag[4][4];
#pragma unroll
  for (int ct = 0; ct < 4; ++ct) {
    int feat = w * 64 + ct * 16 + lcol;
#pragma unroll
    for (int kk = 0; kk < 4; ++kk)
      afrag[ct][kk] = *(const s16x8*)(Wb + (size_t)feat * 128 + kk * 32 + kgrp * 8);
  }

  __syncthreads();

  for (int t = 0; t < 8; ++t) {
    int grow = mbase + t * 16 + lcol;
    int ga = grow < n ? grow : n - 1;
    const float* brow = msg + ((size_t)ga + (size_t)n) * 128;  // msg_tgt row

    s16x8 bfrag[4];
#pragma unroll
    for (int kk = 0; kk < 4; ++kk)
      bfrag[kk] = pack_bf16x8(brow + kk * 32 + kgrp * 8);

    // compute + stage into LDS
#pragma unroll
    for (int ct = 0; ct < 4; ++ct) {
      f32x4 acc = {0.f, 0.f, 0.f, 0.f};
#pragma unroll
      for (int kk = 0; kk < 4; ++kk)
        acc = __builtin_amdgcn_mfma_f32_16x16x32_bf16(afrag[ct][kk], bfrag[kk], acc, 0, 0, 0);
      int f0 = w * 64 + ct * 16 + kgrp * 4;
      float a = att_lds[t * 16 + lcol][f0 >> 5];
      *(f32x4*)&stg[0][lcol][f0] = acc * a;
      *(f32x4*)&stg[1][lcol][f0] = acc;
    }
    asm volatile("s_waitcnt lgkmcnt(0)" ::: "memory");  // LDS writes visible
    __builtin_amdgcn_s_barrier();                       // no vmcnt drain

    // wave w writes edges er = rnd*4 + w; 1 KB contiguous NT per store
#pragma unroll
    for (int rnd = 0; rnd < 4; ++rnd) {
      int er = rnd * 4 + w;
      int ge = mbase + t * 16 + er;
      if (ge < n) {
        f32x4 v0 = *(const f32x4*)(&stg[0][er][0] + l * 4);
        __builtin_nontemporal_store(v0, (f32x4*)(out + (size_t)ge * 256 + l * 4));
        f32x4 v1 = *(const f32x4*)(&stg[1][er][0] + l * 4);
        __builtin_nontemporal_store(v1, (f32x4*)(out + ((size_t)ge + (size_t)n) * 256 + l * 4));
      }
    }
    asm volatile("s_waitcnt lgkmcnt(0)" ::: "memory");  // LDS reads done
    __builtin_amdgcn_s_barrier();                       // stores stay in flight
  }
}

// ---------------------------------------------------------------------------
extern "C" void kernel_launch(void* const* d_in, const int* in_sizes, int n_in,
                              void* d_out, int out_size, void* d_ws, size_t ws_size,
                              hipStream_t stream) {
  const float* messages = (const float*)d_in[0];
  const float* W        = (const float*)d_in[1];
  const float* a_src    = (const float*)d_in[2];
  const float* a_tgt    = (const float*)d_in[3];
  const int*   index    = (const int*)d_in[4];
  int n = in_sizes[4];  // n_edges = 250000

  char* ws = (char*)d_ws;
  unsigned short* Wb     = (unsigned short*)(ws);             // 64 KB
  unsigned short* wb_cat = (unsigned short*)(ws + 65536);     // 4 KB
  unsigned short* denom  = (unsigned short*)(ws + 69632);     // 800 KB (bf16)
  float* ex              = (float*)(ws + 69632 + 1600000);    // 8 MB
  float* out = (float*)d_out;

  prep_kernel<<<(NSEG * 8 + 255) / 256, 256, 0, stream>>>(W, a_src, a_tgt, Wb,
                                                          wb_cat, denom);
  score_kernel<<<(n + 63) / 64, 256, 0, stream>>>(messages, index, wb_cat, ex,
                                                  denom, n);
  gemm_kernel<<<(n + 127) / 128, 256, 0, stream>>>(messages, index, Wb, ex,
                                                   denom, out, n);
}

// Round 17
// 168.682 us; speedup vs baseline: 1.8110x; 1.0038x over previous
//
#include <hip/hip_runtime.h>
#include <hip/hip_bf16.h>

#define NSEG 50000

typedef __attribute__((ext_vector_type(4))) float f32x4;
typedef __attribute__((ext_vector_type(8))) short s16x8;

static __device__ __forceinline__ unsigned short f2bf(float f) {
  unsigned int u = __float_as_uint(f);
  u += 0x7fffu + ((u >> 16) & 1u);   // round-to-nearest-even
  return (unsigned short)(u >> 16);
}

static __device__ __forceinline__ s16x8 pack_raw(const f32x4& a, const f32x4& b) {
  s16x8 v;
  v[0] = (short)f2bf(a.x); v[1] = (short)f2bf(a.y);
  v[2] = (short)f2bf(a.z); v[3] = (short)f2bf(a.w);
  v[4] = (short)f2bf(b.x); v[5] = (short)f2bf(b.y);
  v[6] = (short)f2bf(b.z); v[7] = (short)f2bf(b.w);
  return v;
}

static __device__ __forceinline__ s16x8 pack_bf16x8(const float* p) {
  f32x4 p0 = *(const f32x4*)(p);
  f32x4 p1 = *(const f32x4*)(p + 4);
  return pack_raw(p0, p1);
}

// packed bf16 atomic add: one 4 B atomic covers 2 heads
static __device__ __forceinline__ void atomic_pk_add_bf16(unsigned short* addr,
                                                          unsigned int packed2) {
  asm volatile("global_atomic_pk_add_bf16 %0, %1, off"
               :: "v"(addr), "v"(packed2) : "memory");
}

// ---------------------------------------------------------------------------
// prep: Wb = bf16(W) [256x128];  wb_cat[16][128] bf16.  (denom via memset)
// ---------------------------------------------------------------------------
__global__ __launch_bounds__(256) void prep_kernel(
    const float* __restrict__ W, const float* __restrict__ a_src,
    const float* __restrict__ a_tgt, unsigned short* __restrict__ Wb,
    unsigned short* __restrict__ wb_cat) {
  int t = blockIdx.x * 256 + threadIdx.x;
  if (t < 32768) Wb[t] = f2bf(W[t]);
  if (t < 2048) {
    int row = t >> 7, k = t & 127;
    int h = row & 7;
    const float* a = (row < 8) ? a_src : a_tgt;
    float acc = 0.f;
    for (int f = 0; f < 32; ++f) acc += W[(h * 32 + f) * 128 + k] * a[h * 32 + f];
    wb_cat[t] = f2bf(acc);
  }
}

// ---------------------------------------------------------------------------
// score: MFMA, A = wb_cat (16 rows x 128 K), B = msg rows (K x 16 edges).
// R17: ALL 16 raw loads issued upfront (max MLP), then pack+MFMA.
// msg_src NT (no LLC alloc); msg_tgt cached. Packed-bf16 atomic denom.
// ---------------------------------------------------------------------------
__global__ __launch_bounds__(256) void score_kernel(
    const float* __restrict__ msg, const int* __restrict__ index,
    const unsigned short* __restrict__ wb_cat, float* __restrict__ ex,
    unsigned short* __restrict__ denom, int n) {
  int tid = threadIdx.x;
  int w = tid >> 6, l = tid & 63;
  int lcol = l & 15;
  int kgrp = l >> 4;
  int ge = blockIdx.x * 64 + w * 16 + lcol;
  int ga = ge < n ? ge : n - 1;
  const float* rs = msg + (size_t)ga * 128 + kgrp * 8;                // src
  const float* rt = msg + ((size_t)ga + (size_t)n) * 128 + kgrp * 8;  // tgt

  // issue ALL global loads first — 16 outstanding per thread
  f32x4 rawS[8], rawT[8];
#pragma unroll
  for (int kk = 0; kk < 4; ++kk) {
    rawS[kk * 2]     = __builtin_nontemporal_load((const f32x4*)(rs + kk * 32));
    rawS[kk * 2 + 1] = __builtin_nontemporal_load((const f32x4*)(rs + kk * 32 + 4));
    rawT[kk * 2]     = *(const f32x4*)(rt + kk * 32);
    rawT[kk * 2 + 1] = *(const f32x4*)(rt + kk * 32 + 4);
  }

  s16x8 afrag[4];
#pragma unroll
  for (int kk = 0; kk < 4; ++kk)
    afrag[kk] = *(const s16x8*)(wb_cat + lcol * 128 + kk * 32 + kgrp * 8);

  f32x4 ds = {0.f, 0.f, 0.f, 0.f};
  f32x4 dt = {0.f, 0.f, 0.f, 0.f};
#pragma unroll
  for (int kk = 0; kk < 4; ++kk) {
    s16x8 bs = pack_raw(rawS[kk * 2], rawS[kk * 2 + 1]);
    ds = __builtin_amdgcn_mfma_f32_16x16x32_bf16(afrag[kk], bs, ds, 0, 0, 0);
    s16x8 bt = pack_raw(rawT[kk * 2], rawT[kk * 2 + 1]);
    dt = __builtin_amdgcn_mfma_f32_16x16x32_bf16(afrag[kk], bt, dt, 0, 0, 0);
  }

  f32x4 evv;
#pragma unroll
  for (int r = 0; r < 4; ++r) {
    float tv = __shfl_xor(dt[r], 32);
    float s = ds[r] + tv;
    s = s > 0.f ? s : 0.2f * s;         // leaky_relu, NEG_SLOPE=0.2
    evv[r] = __expf(s);
  }
  if (kgrp < 2 && ge < n) {
    int seg = index[ge];
    unsigned int p0 = (unsigned int)f2bf(evv[0]) | ((unsigned int)f2bf(evv[1]) << 16);
    unsigned int p1 = (unsigned int)f2bf(evv[2]) | ((unsigned int)f2bf(evv[3]) << 16);
    atomic_pk_add_bf16(&denom[seg * 8 + kgrp * 4], p0);
    atomic_pk_add_bf16(&denom[seg * 8 + kgrp * 4 + 2], p1);
    *(f32x4*)(ex + (size_t)ge * 8 + kgrp * 4) = evv;
  }
}

// ---------------------------------------------------------------------------
// gemm: 128-edge blocks (8 t-tiles), LDS-bounce + 1 KB NT stores + raw
// barriers. denom read as bf16.
// ---------------------------------------------------------------------------
__global__ __launch_bounds__(256) void gemm_kernel(
    const float* __restrict__ msg, const int* __restrict__ index,
    const unsigned short* __restrict__ Wb, const float* __restrict__ ex,
    const unsigned short* __restrict__ denom, float* __restrict__ out, int n) {
  __shared__ float att_lds[128][9];
  __shared__ float stg[2][16][260];
  int tid = threadIdx.x;
  int w = tid >> 6, l = tid & 63;
  int lcol = l & 15, kgrp = l >> 4;
  int mbase = blockIdx.x * 128;

  for (int i = tid; i < 1024; i += 256) {
    int r = i >> 3, h = i & 7;
    int ge = mbase + r;
    float a = 0.f;
    if (ge < n) {
      int seg = index[ge];
      float dv = __uint_as_float(((unsigned int)denom[seg * 8 + h]) << 16);
      a = ex[(size_t)ge * 8 + h] / (dv + 1e-16f);
    }
    att_lds[r][h] = a;
  }

  // A-frags: wave w's 4 feature-tiles, loaded once (Wb is L2-resident)
  s16x8 afrag[4][4];
#pragma unroll
  for (int ct = 0; ct < 4; ++ct) {
    int feat = w * 64 + ct * 16 + lcol;
#pragma unroll
    for (int kk = 0; kk < 4; ++kk)
      afrag[ct][kk] = *(const s16x8*)(Wb + (size_t)feat * 128 + kk * 32 + kgrp * 8);
  }

  __syncthreads();

  for (int t = 0; t < 8; ++t) {
    int grow = mbase + t * 16 + lcol;
    int ga = grow < n ? grow : n - 1;
    const float* brow = msg + ((size_t)ga + (size_t)n) * 128;  // msg_tgt row

    s16x8 bfrag[4];
#pragma unroll
    for (int kk = 0; kk < 4; ++kk)
      bfrag[kk] = pack_bf16x8(brow + kk * 32 + kgrp * 8);

    // compute + stage into LDS
#pragma unroll
    for (int ct = 0; ct < 4; ++ct) {
      f32x4 acc = {0.f, 0.f, 0.f, 0.f};
#pragma unroll
      for (int kk = 0; kk < 4; ++kk)
        acc = __builtin_amdgcn_mfma_f32_16x16x32_bf16(afrag[ct][kk], bfrag[kk], acc, 0, 0, 0);
      int f0 = w * 64 + ct * 16 + kgrp * 4;
      float a = att_lds[t * 16 + lcol][f0 >> 5];
      *(f32x4*)&stg[0][lcol][f0] = acc * a;
      *(f32x4*)&stg[1][lcol][f0] = acc;
    }
    asm volatile("s_waitcnt lgkmcnt(0)" ::: "memory");  // LDS writes visible
    __builtin_amdgcn_s_barrier();                       // no vmcnt drain

    // wave w writes edges er = rnd*4 + w; 1 KB contiguous NT per store
#pragma unroll
    for (int rnd = 0; rnd < 4; ++rnd) {
      int er = rnd * 4 + w;
      int ge = mbase + t * 16 + er;
      if (ge < n) {
        f32x4 v0 = *(const f32x4*)(&stg[0][er][0] + l * 4);
        __builtin_nontemporal_store(v0, (f32x4*)(out + (size_t)ge * 256 + l * 4));
        f32x4 v1 = *(const f32x4*)(&stg[1][er][0] + l * 4);
        __builtin_nontemporal_store(v1, (f32x4*)(out + ((size_t)ge + (size_t)n) * 256 + l * 4));
      }
    }
    asm volatile("s_waitcnt lgkmcnt(0)" ::: "memory");  // LDS reads done
    __builtin_amdgcn_s_barrier();                       // stores stay in flight
  }
}

// ---------------------------------------------------------------------------
extern "C" void kernel_launch(void* const* d_in, const int* in_sizes, int n_in,
                              void* d_out, int out_size, void* d_ws, size_t ws_size,
                              hipStream_t stream) {
  const float* messages = (const float*)d_in[0];
  const float* W        = (const float*)d_in[1];
  const float* a_src    = (const float*)d_in[2];
  const float* a_tgt    = (const float*)d_in[3];
  const int*   index    = (const int*)d_in[4];
  int n = in_sizes[4];  // n_edges = 250000

  char* ws = (char*)d_ws;
  unsigned short* Wb     = (unsigned short*)(ws);             // 64 KB
  unsigned short* wb_cat = (unsigned short*)(ws + 65536);     // 4 KB
  unsigned short* denom  = (unsigned short*)(ws + 69632);     // 800 KB (bf16)
  float* ex              = (float*)(ws + 69632 + 1600000);    // 8 MB
  float* out = (float*)d_out;

  hipMemsetAsync(denom, 0, NSEG * 8 * sizeof(unsigned short), stream);
  prep_kernel<<<128, 256, 0, stream>>>(W, a_src, a_tgt, Wb, wb_cat);
  score_kernel<<<(n + 63) / 64, 256, 0, stream>>>(messages, index, wb_cat, ex,
                                                  denom, n);
  gemm_kernel<<<(n + 127) / 128, 256, 0, stream>>>(messages, index, Wb, ex,
                                                   denom, out, n);
}